// Round 2
// baseline (282.951 us; speedup 1.0000x reference)
//
#include <hip/hip_runtime.h>
#include <hip/hip_bf16.h>

#define HEADS 16
#define KEY   64
#define BB    2
#define SS    2048
#define DD    1024
#define NCOL  1024   // HEADS*KEY

typedef __attribute__((ext_vector_type(8))) short bf16x8;
typedef __attribute__((ext_vector_type(4))) float f32x4;
typedef __attribute__((ext_vector_type(8))) unsigned short u16x8;

typedef const __attribute__((address_space(1))) void* gas_ptr;
typedef __attribute__((address_space(3))) void* las_ptr;

__device__ __forceinline__ void gload_lds16(const void* g, void* l) {
  __builtin_amdgcn_global_load_lds((gas_ptr)g, (las_ptr)l, 16, 0, 0);
}

__device__ __forceinline__ unsigned short f2bf(float f) {
  unsigned u = __builtin_bit_cast(unsigned, f);
  u = (u + 0x7FFFu + ((u >> 16) & 1u)) >> 16;
  return (unsigned short)u;
}

__device__ __forceinline__ f32x4 mfma_bf16(bf16x8 a, bf16x8 b, f32x4 c) {
  return __builtin_amdgcn_mfma_f32_16x16x32_bf16(a, b, c, 0, 0, 0);
}

// ---------------- fp32 -> bf16 convert (8 elems/thread) ----------------
__global__ __launch_bounds__(256) void cvt_bf16(const float* __restrict__ in,
                                                unsigned short* __restrict__ out,
                                                int n8) {
  int i = blockIdx.x * blockDim.x + threadIdx.x;
  if (i >= n8) return;
  const float4* p = reinterpret_cast<const float4*>(in) + (size_t)i * 2;
  float4 a = p[0], b = p[1];
  u16x8 o;
  o[0] = f2bf(a.x); o[1] = f2bf(a.y); o[2] = f2bf(a.z); o[3] = f2bf(a.w);
  o[4] = f2bf(b.x); o[5] = f2bf(b.y); o[6] = f2bf(b.z); o[7] = f2bf(b.w);
  reinterpret_cast<u16x8*>(out)[i] = o;
}

// ---------------- W (K x N) fp32 -> W^T (N x K) bf16 ----------------
__global__ __launch_bounds__(1024) void trw(const float* __restrict__ W0,
                                            const float* __restrict__ W1,
                                            const float* __restrict__ W2,
                                            unsigned short* __restrict__ T0,
                                            unsigned short* __restrict__ T1,
                                            unsigned short* __restrict__ T2) {
  const float* W = blockIdx.z == 0 ? W0 : (blockIdx.z == 1 ? W1 : W2);
  unsigned short* T = blockIdx.z == 0 ? T0 : (blockIdx.z == 1 ? T1 : T2);
  __shared__ float tile[32][33];
  int tx = threadIdx.x, ty = threadIdx.y;
  tile[ty][tx] = W[(size_t)(blockIdx.y * 32 + ty) * DD + blockIdx.x * 32 + tx];
  __syncthreads();
  T[(size_t)(blockIdx.x * 32 + ty) * DD + blockIdx.y * 32 + tx] = f2bf(tile[tx][ty]);
}

// ---------------- V-proj transpose: vwp[b*2048+s][h*64+d] -> vt[(b*16+h)*64+d][s] ----------------
__global__ __launch_bounds__(1024) void trv(const unsigned short* __restrict__ vwp,
                                            unsigned short* __restrict__ vt) {
  __shared__ unsigned short tile[32][33];
  const int bh = blockIdx.z, b = bh >> 4, h = bh & 15;
  const int s0 = blockIdx.x * 32, d0 = blockIdx.y * 32;
  const int tx = threadIdx.x, ty = threadIdx.y;
  tile[ty][tx] = vwp[(size_t)(b * SS + s0 + ty) * NCOL + h * KEY + d0 + tx];
  __syncthreads();
  vt[((size_t)bh * KEY + d0 + ty) * SS + s0 + tx] = tile[tx][ty];
}

// ---------------- projection GEMM: O(M,N) = X(M,K) * WT(N,K)^T, bf16 ----------------
__global__ __launch_bounds__(256) void gemm_proj(
    const unsigned short* __restrict__ X0, const unsigned short* __restrict__ X1,
    const unsigned short* __restrict__ X2,
    const unsigned short* __restrict__ W0, const unsigned short* __restrict__ W1,
    const unsigned short* __restrict__ W2,
    unsigned short* __restrict__ O0, unsigned short* __restrict__ O1,
    unsigned short* __restrict__ O2) {
  const unsigned short* X; const unsigned short* WT; unsigned short* O;
  if (blockIdx.z == 0)      { X = X0; WT = W0; O = O0; }
  else if (blockIdx.z == 1) { X = X1; WT = W1; O = O1; }
  else                      { X = X2; WT = W2; O = O2; }

  __shared__ __align__(16) unsigned short As[128 * 32];
  __shared__ __align__(16) unsigned short Bs[128 * 32];

  const int tid = threadIdx.x;
  const int w = tid >> 6, l = tid & 63;
  const int m0 = blockIdx.x * 128, n0 = blockIdx.y * 128;
  const int wm = (w >> 1) * 64, wn = (w & 1) * 64;
  const int g = l >> 4, c = l & 15;

  const int srow = tid >> 2;
  const int scol = (tid & 3) * 8;

  f32x4 acc[4][4] = {};

  for (int k0 = 0; k0 < DD; k0 += 32) {
#pragma unroll
    for (int i = 0; i < 2; ++i) {
      gload_lds16(X + (size_t)(m0 + i * 64 + srow) * DD + k0 + scol,
                  (char*)As + i * 4096 + w * 1024);
      gload_lds16(WT + (size_t)(n0 + i * 64 + srow) * DD + k0 + scol,
                  (char*)Bs + i * 4096 + w * 1024);
    }
    __syncthreads();
    bf16x8 af[4], bfr[4];
    const int kb = g * 8;
#pragma unroll
    for (int mi = 0; mi < 4; mi++)
      af[mi] = *reinterpret_cast<const bf16x8*>(&As[(wm + mi * 16 + c) * 32 + kb]);
#pragma unroll
    for (int ni = 0; ni < 4; ni++)
      bfr[ni] = *reinterpret_cast<const bf16x8*>(&Bs[(wn + ni * 16 + c) * 32 + kb]);
#pragma unroll
    for (int mi = 0; mi < 4; mi++)
#pragma unroll
      for (int ni = 0; ni < 4; ni++)
        acc[mi][ni] = mfma_bf16(af[mi], bfr[ni], acc[mi][ni]);
    __syncthreads();
  }

#pragma unroll
  for (int mi = 0; mi < 4; mi++)
#pragma unroll
    for (int ni = 0; ni < 4; ni++)
#pragma unroll
      for (int r = 0; r < 4; r++) {
        int row = m0 + wm + mi * 16 + g * 4 + r;
        int col = n0 + wn + ni * 16 + c;
        O[(size_t)row * NCOL + col] = f2bf(acc[mi][ni][r]);
      }
}

// ---------------- causal flash attention (2-phase dbuf, pre-transposed V) ----------------
// grid (32, H, B), 256 threads = 4 waves, wave w owns q rows qt*64+w*16..+15.
__global__ __launch_bounds__(256) void attn(const unsigned short* __restrict__ qw,
                                            const unsigned short* __restrict__ kw,
                                            const unsigned short* __restrict__ vt,
                                            float* __restrict__ out) {
  __shared__ __align__(16) unsigned short Ks[2][64 * 64]; // [kv][d], XOR-swizzled
  __shared__ __align__(16) unsigned short Vs[2][64 * 64]; // [d][kv], XOR-swizzled
  __shared__ __align__(16) unsigned short Plds[4][16 * 64]; // per-wave, XOR-swizzled

  const int tid = threadIdx.x, w = tid >> 6, l = tid & 63;
  const int qt = (int)gridDim.x - 1 - (int)blockIdx.x;  // LPT: heavy tiles first
  const int q0 = qt * 64, h = blockIdx.y, b = blockIdx.z;
  const int g = l >> 4, c = l & 15;

  // Q fragments (A operand): row = lane&15, k = (lane>>4)*8 + j (+32 for ks=1)
  const size_t qbase = ((size_t)(b * SS) + q0 + w * 16 + c) * NCOL + h * KEY;
  bf16x8 qf[2];
  qf[0] = *reinterpret_cast<const bf16x8*>(qw + qbase + g * 8);
  qf[1] = *reinterpret_cast<const bf16x8*>(qw + qbase + g * 8 + 32);

  f32x4 oacc[4] = {};
  float m[4], lsum[4];
#pragma unroll
  for (int r = 0; r < 4; r++) { m[r] = -1e30f; lsum[r] = 0.f; }

  // staging geometry: dest row = j*32 + w*8 + (l>>3), col granule (l&7), source
  // column pre-swizzled so reads use granule ^= (row&7).
  const int krow_base = w * 8 + (l >> 3);
  const int kcol_sw = 8 * ((l & 7) ^ (l >> 3));
  const size_t kbase = (size_t)(b * SS) * NCOL + h * KEY;
  const size_t vbase = (size_t)(b * HEADS + h) * KEY * SS;

  const int nt = qt + 1;  // number of 64-wide KV tiles

  // prologue: stage tile 0 into buf 0
#pragma unroll
  for (int j = 0; j < 2; ++j) {
    gload_lds16(kw + kbase + (size_t)(j * 32 + krow_base) * NCOL + kcol_sw,
                (char*)Ks[0] + j * 4096 + w * 1024);
    gload_lds16(vt + vbase + (size_t)(j * 32 + krow_base) * SS + kcol_sw,
                (char*)Vs[0] + j * 4096 + w * 1024);
  }
  __syncthreads();

  int cur = 0;
  for (int t0 = 0; t0 < nt; ++t0) {
    const int kv0 = t0 * 64;
    // ---- issue next tile's async stages (overlap with compute) ----
    if (t0 + 1 < nt) {
      const int nkv = kv0 + 64;
      const int nxt = cur ^ 1;
#pragma unroll
      for (int j = 0; j < 2; ++j) {
        gload_lds16(kw + kbase + (size_t)(nkv + j * 32 + krow_base) * NCOL + kcol_sw,
                    (char*)Ks[nxt] + j * 4096 + w * 1024);
        gload_lds16(vt + vbase + (size_t)(j * 32 + krow_base) * SS + nkv + kcol_sw,
                    (char*)Vs[nxt] + j * 4096 + w * 1024);
      }
    }

    // ---- S = Q K^T (per wave: 16 q x 64 kv) ----
    f32x4 sacc[4] = {};
#pragma unroll
    for (int t = 0; t < 4; t++) {
#pragma unroll
      for (int ks = 0; ks < 2; ks++) {
        int off = ((g | (ks << 2)) ^ (c & 7)) << 3;
        bf16x8 kf = *reinterpret_cast<const bf16x8*>(&Ks[cur][(t * 16 + c) * 64 + off]);
        sacc[t] = mfma_bf16(qf[ks], kf, sacc[t]);
      }
    }

    // ---- online softmax (exp2 domain) ----
    const float SC = 0.125f * 1.44269504089f;
    float p[4][4], pm[4];
#pragma unroll
    for (int r = 0; r < 4; r++) pm[r] = -1e30f;
    const int qrow = q0 + w * 16 + g * 4;
    const bool diag = (t0 == nt - 1);
#pragma unroll
    for (int t = 0; t < 4; t++) {
      int kv = kv0 + t * 16 + c;
#pragma unroll
      for (int r = 0; r < 4; r++) {
        float s = sacc[t][r] * SC;
        if (diag && kv > qrow + r) s = -1e30f;
        p[t][r] = s;
        pm[r] = fmaxf(pm[r], s);
      }
    }
    bool grow = false;
#pragma unroll
    for (int r = 0; r < 4; r++) {
      float v = pm[r];
      v = fmaxf(v, __shfl_xor(v, 1));
      v = fmaxf(v, __shfl_xor(v, 2));
      v = fmaxf(v, __shfl_xor(v, 4));
      v = fmaxf(v, __shfl_xor(v, 8));
      pm[r] = v;
      grow |= (v > m[r]);
    }
    if (__ballot(grow)) {
#pragma unroll
      for (int r = 0; r < 4; r++) {
        float mn = fmaxf(m[r], pm[r]);
        float alpha = exp2f(m[r] - mn);
        m[r] = mn;
        lsum[r] *= alpha;
#pragma unroll
        for (int t = 0; t < 4; t++) oacc[t][r] *= alpha;
      }
    }
    float rs[4] = {0.f, 0.f, 0.f, 0.f};
#pragma unroll
    for (int t = 0; t < 4; t++)
#pragma unroll
      for (int r = 0; r < 4; r++) {
        float e = exp2f(p[t][r] - m[r]);
        p[t][r] = e;
        rs[r] += e;
      }
#pragma unroll
    for (int r = 0; r < 4; r++) {
      float v = rs[r];
      v += __shfl_xor(v, 1);
      v += __shfl_xor(v, 2);
      v += __shfl_xor(v, 4);
      v += __shfl_xor(v, 8);
      lsum[r] += v;
    }

    // ---- P -> LDS (bf16, XOR-swizzled stride 64), then PV ----
#pragma unroll
    for (int t = 0; t < 4; t++)
#pragma unroll
      for (int r = 0; r < 4; r++) {
        int row = g * 4 + r;
        Plds[w][row * 64 + ((t * 16 + c) ^ ((row & 7) << 3))] = f2bf(p[t][r]);
      }

    bf16x8 pf[2];
#pragma unroll
    for (int ks = 0; ks < 2; ks++)
      pf[ks] = *reinterpret_cast<const bf16x8*>(
          &Plds[w][c * 64 + (((g | (ks << 2)) ^ (c & 7)) << 3)]);
#pragma unroll
    for (int t = 0; t < 4; t++) {
#pragma unroll
      for (int ks = 0; ks < 2; ks++) {
        int off = ((g | (ks << 2)) ^ (c & 7)) << 3;
        bf16x8 vf = *reinterpret_cast<const bf16x8*>(&Vs[cur][(t * 16 + c) * 64 + off]);
        oacc[t] = mfma_bf16(pf[ks], vf, oacc[t]);
      }
    }
    __syncthreads();  // drains vmcnt(0): next tile's stages complete
    cur ^= 1;
  }

  // ---- epilogue: normalize + store fp32 ----
#pragma unroll
  for (int r = 0; r < 4; r++) {
    float inv = 1.0f / lsum[r];
    int qrow = q0 + w * 16 + g * 4 + r;
    float* op = out + ((size_t)(b * SS) + qrow) * NCOL + h * KEY;
#pragma unroll
    for (int t = 0; t < 4; t++)
      op[t * 16 + c] = oacc[t][r] * inv;
  }
}

extern "C" void kernel_launch(void* const* d_in, const int* in_sizes, int n_in,
                              void* d_out, int out_size, void* d_ws, size_t ws_size,
                              hipStream_t stream) {
  const float* q  = (const float*)d_in[0];
  const float* k  = (const float*)d_in[1];
  const float* v  = (const float*)d_in[2];
  const float* Wq = (const float*)d_in[3];
  const float* Wk = (const float*)d_in[4];
  const float* Wv = (const float*)d_in[5];
  float* out = (float*)d_out;

  unsigned short* ws  = (unsigned short*)d_ws;
  const size_t ACT = (size_t)4 * 1024 * 1024;
  const size_t WEL = (size_t)1024 * 1024;
  unsigned short* qbf = ws;
  unsigned short* kbf = qbf + ACT;
  unsigned short* vbf = kbf + ACT;
  unsigned short* WqT = vbf + ACT;
  unsigned short* WkT = WqT + WEL;
  unsigned short* WvT = WkT + WEL;
  unsigned short* qwp = WvT + WEL;
  unsigned short* kwp = qwp + ACT;
  unsigned short* vwp = kwp + ACT;
  unsigned short* vtb = qbf;  // reuse: qbf dead after gemm_proj

  cvt_bf16<<<2048, 256, 0, stream>>>(q, qbf, 524288);
  cvt_bf16<<<2048, 256, 0, stream>>>(k, kbf, 524288);
  cvt_bf16<<<2048, 256, 0, stream>>>(v, vbf, 524288);
  trw<<<dim3(32, 32, 3), dim3(32, 32), 0, stream>>>(Wq, Wk, Wv, WqT, WkT, WvT);
  gemm_proj<<<dim3(32, 8, 3), 256, 0, stream>>>(qbf, kbf, vbf, WqT, WkT, WvT,
                                                qwp, kwp, vwp);
  trv<<<dim3(64, 2, 32), dim3(32, 32), 0, stream>>>(vwp, vtb);
  attn<<<dim3(32, 16, 2), 256, 0, stream>>>(qwp, kwp, vtb, out);
}

// Round 3
// 219.151 us; speedup vs baseline: 1.2911x; 1.2911x over previous
//
#include <hip/hip_runtime.h>
#include <hip/hip_bf16.h>

#define HEADS 16
#define KEY   64
#define BB    2
#define SS    2048
#define DD    1024
#define NCOL  1024   // HEADS*KEY

typedef __attribute__((ext_vector_type(8))) short bf16x8;
typedef __attribute__((ext_vector_type(4))) float f32x4;
typedef __attribute__((ext_vector_type(8))) unsigned short u16x8;

typedef const __attribute__((address_space(1))) void* gas_ptr;
typedef __attribute__((address_space(3))) void* las_ptr;

__device__ __forceinline__ void gload_lds16(const void* g, void* l) {
  __builtin_amdgcn_global_load_lds((gas_ptr)g, (las_ptr)l, 16, 0, 0);
}

__device__ __forceinline__ unsigned short f2bf(float f) {
  unsigned u = __builtin_bit_cast(unsigned, f);
  u = (u + 0x7FFFu + ((u >> 16) & 1u)) >> 16;
  return (unsigned short)u;
}

__device__ __forceinline__ float bf2f(unsigned short u) {
  return __builtin_bit_cast(float, (unsigned)u << 16);
}

__device__ __forceinline__ unsigned cvtpk(float lo, float hi) {
  unsigned r;
  asm("v_cvt_pk_bf16_f32 %0, %1, %2" : "=v"(r) : "v"(lo), "v"(hi));
  return r;
}

__device__ __forceinline__ f32x4 mfma_bf16(bf16x8 a, bf16x8 b, f32x4 c) {
  return __builtin_amdgcn_mfma_f32_16x16x32_bf16(a, b, c, 0, 0, 0);
}

// ---------------- fp32 -> bf16 convert (8 elems/thread) ----------------
__global__ __launch_bounds__(256) void cvt_bf16(const float* __restrict__ in,
                                                unsigned short* __restrict__ out,
                                                int n8) {
  int i = blockIdx.x * blockDim.x + threadIdx.x;
  if (i >= n8) return;
  const float4* p = reinterpret_cast<const float4*>(in) + (size_t)i * 2;
  float4 a = p[0], b = p[1];
  u16x8 o;
  o[0] = f2bf(a.x); o[1] = f2bf(a.y); o[2] = f2bf(a.z); o[3] = f2bf(a.w);
  o[4] = f2bf(b.x); o[5] = f2bf(b.y); o[6] = f2bf(b.z); o[7] = f2bf(b.w);
  reinterpret_cast<u16x8*>(out)[i] = o;
}

// ---------------- W (K x N) fp32 -> W^T (N x K) bf16 ----------------
__global__ __launch_bounds__(1024) void trw(const float* __restrict__ W0,
                                            const float* __restrict__ W1,
                                            const float* __restrict__ W2,
                                            unsigned short* __restrict__ T0,
                                            unsigned short* __restrict__ T1,
                                            unsigned short* __restrict__ T2) {
  const float* W = blockIdx.z == 0 ? W0 : (blockIdx.z == 1 ? W1 : W2);
  unsigned short* T = blockIdx.z == 0 ? T0 : (blockIdx.z == 1 ? T1 : T2);
  __shared__ float tile[32][33];
  int tx = threadIdx.x, ty = threadIdx.y;
  tile[ty][tx] = W[(size_t)(blockIdx.y * 32 + ty) * DD + blockIdx.x * 32 + tx];
  __syncthreads();
  T[(size_t)(blockIdx.x * 32 + ty) * DD + blockIdx.y * 32 + tx] = f2bf(tile[tx][ty]);
}

// ---------------- V-proj transpose: vwp[b*2048+s][h*64+d] -> vt[(b*16+h)*64+d][s] ----------------
__global__ __launch_bounds__(1024) void trv(const unsigned short* __restrict__ vwp,
                                            unsigned short* __restrict__ vt) {
  __shared__ unsigned short tile[32][33];
  const int bh = blockIdx.z, b = bh >> 4, h = bh & 15;
  const int s0 = blockIdx.x * 32, d0 = blockIdx.y * 32;
  const int tx = threadIdx.x, ty = threadIdx.y;
  tile[ty][tx] = vwp[(size_t)(b * SS + s0 + ty) * NCOL + h * KEY + d0 + tx];
  __syncthreads();
  vt[((size_t)bh * KEY + d0 + ty) * SS + s0 + tx] = tile[tx][ty];
}

// ---------------- projection GEMM: O(M,N) = X(M,K) * WT(N,K)^T, bf16 ----------------
__global__ __launch_bounds__(256) void gemm_proj(
    const unsigned short* __restrict__ X0, const unsigned short* __restrict__ X1,
    const unsigned short* __restrict__ X2,
    const unsigned short* __restrict__ W0, const unsigned short* __restrict__ W1,
    const unsigned short* __restrict__ W2,
    unsigned short* __restrict__ O0, unsigned short* __restrict__ O1,
    unsigned short* __restrict__ O2) {
  const unsigned short* X; const unsigned short* WT; unsigned short* O;
  if (blockIdx.z == 0)      { X = X0; WT = W0; O = O0; }
  else if (blockIdx.z == 1) { X = X1; WT = W1; O = O1; }
  else                      { X = X2; WT = W2; O = O2; }

  __shared__ __align__(16) unsigned short As[128 * 32];
  __shared__ __align__(16) unsigned short Bs[128 * 32];

  const int tid = threadIdx.x;
  const int w = tid >> 6, l = tid & 63;
  const int m0 = blockIdx.x * 128, n0 = blockIdx.y * 128;
  const int wm = (w >> 1) * 64, wn = (w & 1) * 64;
  const int g = l >> 4, c = l & 15;

  const int srow = tid >> 2;
  const int scol = (tid & 3) * 8;

  f32x4 acc[4][4] = {};

  for (int k0 = 0; k0 < DD; k0 += 32) {
#pragma unroll
    for (int i = 0; i < 2; ++i) {
      gload_lds16(X + (size_t)(m0 + i * 64 + srow) * DD + k0 + scol,
                  (char*)As + i * 4096 + w * 1024);
      gload_lds16(WT + (size_t)(n0 + i * 64 + srow) * DD + k0 + scol,
                  (char*)Bs + i * 4096 + w * 1024);
    }
    __syncthreads();
    bf16x8 af[4], bfr[4];
    const int kb = g * 8;
#pragma unroll
    for (int mi = 0; mi < 4; mi++)
      af[mi] = *reinterpret_cast<const bf16x8*>(&As[(wm + mi * 16 + c) * 32 + kb]);
#pragma unroll
    for (int ni = 0; ni < 4; ni++)
      bfr[ni] = *reinterpret_cast<const bf16x8*>(&Bs[(wn + ni * 16 + c) * 32 + kb]);
#pragma unroll
    for (int mi = 0; mi < 4; mi++)
#pragma unroll
      for (int ni = 0; ni < 4; ni++)
        acc[mi][ni] = mfma_bf16(af[mi], bfr[ni], acc[mi][ni]);
    __syncthreads();
  }

#pragma unroll
  for (int mi = 0; mi < 4; mi++)
#pragma unroll
    for (int ni = 0; ni < 4; ni++)
#pragma unroll
      for (int r = 0; r < 4; r++) {
        int row = m0 + wm + mi * 16 + g * 4 + r;
        int col = n0 + wn + ni * 16 + c;
        O[(size_t)row * NCOL + col] = f2bf(acc[mi][ni][r]);
      }
}

// ---------------- causal flash attention, split-KV (chunk = 8 tiles of 64) ----------------
// grid (80, H, B). x -> (qt, chunk). 256 threads = 4 waves; wave w owns q rows
// qt*64 + w*16 .. +15. Swapped QK^T: lane (g,c) owns q-row c, kv in registers.
__global__ __launch_bounds__(256) void attn(const unsigned short* __restrict__ qw,
                                            const unsigned short* __restrict__ kw,
                                            const unsigned short* __restrict__ vt,
                                            unsigned short* __restrict__ opart,
                                            float* __restrict__ mlb,
                                            float* __restrict__ out) {
  __shared__ __align__(16) char smem[40960];
  char* KsRaw = smem;                                       // [2][8192] B
  char* VsRaw = smem + 16384;                               // [2][8192] B
  unsigned short* Pl = (unsigned short*)(smem + 32768);     // [4][16*64]
  float* Osc = (float*)smem;                                // epilogue overlay [64][72]

  const int tid = threadIdx.x, w = tid >> 6, l = tid & 63;
  const int g = l >> 4, c = l & 15;
  const int x = blockIdx.x, h = blockIdx.y, b = blockIdx.z;

  int qt, ci, nchunks;
  if (x < 8)       { qt = x;                ci = 0;            nchunks = 1; }
  else if (x < 24) { qt = 8 + ((x - 8) >> 1);  ci = (x - 8) & 1;  nchunks = 2; }
  else if (x < 48) { qt = 16 + (x - 24) / 3;   ci = (x - 24) % 3; nchunks = 3; }
  else             { qt = 24 + ((x - 48) >> 2); ci = (x - 48) & 3; nchunks = 4; }
  const int nt = qt + 1;
  const int t_begin = ci * 8;
  const int t_end = min(t_begin + 8, nt);
  const int q0 = qt * 64;
  const int cid = (b * HEADS + h) * 80 + x;

  // Q fragments (B operand of swapped QK^T): col=lane&15=q, k = g*8+j (+32)
  const int qrow = q0 + w * 16 + c;
  const size_t qbase = ((size_t)(b * SS) + qrow) * NCOL + h * KEY;
  bf16x8 qf[2];
  qf[0] = *reinterpret_cast<const bf16x8*>(qw + qbase + g * 8);
  qf[1] = *reinterpret_cast<const bf16x8*>(qw + qbase + g * 8 + 32);

  f32x4 oacc[4] = {};   // O^T: lane (g,c): d = 16t+4g+r, q = c
  float m = -1e30f, lsum = 0.f;

  const int krow = w * 8 + (l >> 3);
  const int kcsw = 8 * ((l & 7) ^ (l >> 3));
  const size_t kbase = (size_t)(b * SS) * NCOL + h * KEY;
  const size_t vbase = (size_t)(b * HEADS + h) * KEY * SS;

  // prologue: stage tile t_begin into buf 0
  {
    const int kv0 = t_begin * 64;
#pragma unroll
    for (int j = 0; j < 2; ++j) {
      gload_lds16(kw + kbase + (size_t)(kv0 + j * 32 + krow) * NCOL + kcsw,
                  KsRaw + j * 4096 + w * 1024);
      gload_lds16(vt + vbase + (size_t)(j * 32 + krow) * SS + kv0 + kcsw,
                  VsRaw + j * 4096 + w * 1024);
    }
  }
  __syncthreads();

  const float SC = 0.125f * 1.44269504089f;
  unsigned short* Pw = Pl + w * 1024;
  int cur = 0;
  for (int it = t_begin; it < t_end; ++it) {
    if (it + 1 < t_end) {
      const int kv1 = (it + 1) * 64, nx = cur ^ 1;
#pragma unroll
      for (int j = 0; j < 2; ++j) {
        gload_lds16(kw + kbase + (size_t)(kv1 + j * 32 + krow) * NCOL + kcsw,
                    KsRaw + nx * 8192 + j * 4096 + w * 1024);
        gload_lds16(vt + vbase + (size_t)(j * 32 + krow) * SS + kv1 + kcsw,
                    VsRaw + nx * 8192 + j * 4096 + w * 1024);
      }
    }
    const unsigned short* Kc = (const unsigned short*)(KsRaw + cur * 8192);
    const unsigned short* Vc = (const unsigned short*)(VsRaw + cur * 8192);

    // ---- S^T = K Q^T ----
    f32x4 sacc[4] = {};
    __builtin_amdgcn_s_setprio(1);
#pragma unroll
    for (int t = 0; t < 4; t++)
#pragma unroll
      for (int ks = 0; ks < 2; ks++) {
        const int off = ((g | (ks << 2)) ^ (c & 7)) << 3;
        bf16x8 kf = *reinterpret_cast<const bf16x8*>(&Kc[(t * 16 + c) * 64 + off]);
        sacc[t] = mfma_bf16(kf, qf[ks], sacc[t]);
      }
    __builtin_amdgcn_s_setprio(0);

    // ---- online softmax: lane owns q-row c ----
    float p[4][4], pm = -3.0e38f;
    const bool dg = (it == nt - 1);
#pragma unroll
    for (int t = 0; t < 4; t++)
#pragma unroll
      for (int r = 0; r < 4; r++) {
        float s = sacc[t][r] * SC;
        if (dg && (it * 64 + 16 * t + 4 * g + r > qrow)) s = -3.0e38f;
        p[t][r] = s;
        pm = fmaxf(pm, s);
      }
    pm = fmaxf(pm, __shfl_xor(pm, 16));
    pm = fmaxf(pm, __shfl_xor(pm, 32));
    if (__ballot(pm > m)) {
      float mn = fmaxf(m, pm);
      float al = exp2f(m - mn);
      m = mn; lsum *= al;
#pragma unroll
      for (int t = 0; t < 4; t++) oacc[t] *= al;
    }
    float rs = 0.f;
#pragma unroll
    for (int t = 0; t < 4; t++)
#pragma unroll
      for (int r = 0; r < 4; r++) {
        float e = exp2f(p[t][r] - m);
        p[t][r] = e;
        rs += e;
      }
    rs += __shfl_xor(rs, 16);
    rs += __shfl_xor(rs, 32);
    lsum += rs;

    // ---- P (bf16) -> per-wave LDS [q=c][kv], XOR-swizzled ----
#pragma unroll
    for (int t = 0; t < 4; t++)
#pragma unroll
      for (int rr = 0; rr < 2; rr++) {
        unsigned pk = cvtpk(p[t][2 * rr], p[t][2 * rr + 1]);
        int col = 16 * t + 4 * g + 2 * rr;
        *reinterpret_cast<unsigned*>(&Pw[c * 64 + (col ^ ((c & 7) << 3))]) = pk;
      }
    bf16x8 pf[2];
#pragma unroll
    for (int ks = 0; ks < 2; ks++)
      pf[ks] = *reinterpret_cast<const bf16x8*>(
          &Pw[c * 64 + (((g | (ks << 2)) ^ (c & 7)) << 3)]);

    // ---- O^T += V^T P^T ----
    __builtin_amdgcn_s_setprio(1);
#pragma unroll
    for (int t = 0; t < 4; t++)
#pragma unroll
      for (int ks = 0; ks < 2; ks++) {
        const int off = ((g | (ks << 2)) ^ (c & 7)) << 3;
        bf16x8 vf = *reinterpret_cast<const bf16x8*>(&Vc[(t * 16 + c) * 64 + off]);
        oacc[t] = mfma_bf16(vf, pf[ks], oacc[t]);
      }
    __builtin_amdgcn_s_setprio(0);
    __syncthreads();   // also drains next tile's global_load_lds
    cur ^= 1;
  }

  // ---- epilogue: transpose O^T -> O through LDS (stride-72 pad) ----
  const float inv = (nchunks == 1) ? 1.0f / lsum : 1.0f;
#pragma unroll
  for (int t = 0; t < 4; t++)
#pragma unroll
    for (int rr = 0; rr < 2; rr++) {
      float2 v2 = make_float2(oacc[t][2 * rr] * inv, oacc[t][2 * rr + 1] * inv);
      *reinterpret_cast<float2*>(&Osc[(w * 16 + c) * 72 + 16 * t + 4 * g + 2 * rr]) = v2;
    }
  if (nchunks > 1 && l < 16) {
    float* mlp = mlb + (size_t)cid * 128 + w * 16 + c;
    mlp[0] = m;
    mlp[64] = lsum;
  }
  __syncthreads();

  const int row = tid >> 2, sg = (tid & 3) << 4;
  if (nchunks == 1) {
    float* op = out + ((size_t)(b * SS) + q0 + row) * NCOL + h * KEY + sg;
#pragma unroll
    for (int kk = 0; kk < 4; kk++)
      reinterpret_cast<float4*>(op)[kk] =
          *reinterpret_cast<const float4*>(&Osc[row * 72 + sg + kk * 4]);
  } else {
    unsigned* pp = reinterpret_cast<unsigned*>(opart + (size_t)cid * 4096 + row * 64 + sg);
#pragma unroll
    for (int e = 0; e < 8; e++)
      pp[e] = cvtpk(Osc[row * 72 + sg + 2 * e], Osc[row * 72 + sg + 2 * e + 1]);
  }
}

// ---------------- split-KV reduce: merge <=4 chunk partials ----------------
__global__ __launch_bounds__(256) void attn_reduce(const unsigned short* __restrict__ opart,
                                                   const float* __restrict__ mlb,
                                                   float* __restrict__ out) {
  const int qt = 8 + blockIdx.x, h = blockIdx.y, b = blockIdx.z;
  int base, nc;
  if (qt < 16)      { base = 8 + 2 * (qt - 8);   nc = 2; }
  else if (qt < 24) { base = 24 + 3 * (qt - 16); nc = 3; }
  else              { base = 48 + 4 * (qt - 24); nc = 4; }
  const int cid0 = (b * HEADS + h) * 80 + base;
  const int row = threadIdx.x >> 2, sg = (threadIdx.x & 3) << 4;

  float mv[4], lv[4], M = -1e30f;
#pragma unroll
  for (int i = 0; i < 4; i++)
    if (i < nc) {
      mv[i] = mlb[(size_t)(cid0 + i) * 128 + row];
      lv[i] = mlb[(size_t)(cid0 + i) * 128 + 64 + row];
      M = fmaxf(M, mv[i]);
    }
  float L = 0.f, acc[16];
#pragma unroll
  for (int e = 0; e < 16; e++) acc[e] = 0.f;
#pragma unroll
  for (int i = 0; i < 4; i++)
    if (i < nc) {
      float s = exp2f(mv[i] - M);
      L += s * lv[i];
      const u16x8* pp = reinterpret_cast<const u16x8*>(
          opart + (size_t)(cid0 + i) * 4096 + row * 64 + sg);
      u16x8 o0 = pp[0], o1 = pp[1];
#pragma unroll
      for (int e = 0; e < 8; e++) {
        acc[e]     += s * bf2f(o0[e]);
        acc[8 + e] += s * bf2f(o1[e]);
      }
    }
  const float inv = 1.0f / L;
  float* op = out + ((size_t)(b * SS) + qt * 64 + row) * NCOL + h * KEY + sg;
#pragma unroll
  for (int kk = 0; kk < 4; kk++) {
    float4 v;
    v.x = acc[4 * kk] * inv;     v.y = acc[4 * kk + 1] * inv;
    v.z = acc[4 * kk + 2] * inv; v.w = acc[4 * kk + 3] * inv;
    reinterpret_cast<float4*>(op)[kk] = v;
  }
}

extern "C" void kernel_launch(void* const* d_in, const int* in_sizes, int n_in,
                              void* d_out, int out_size, void* d_ws, size_t ws_size,
                              hipStream_t stream) {
  const float* q  = (const float*)d_in[0];
  const float* k  = (const float*)d_in[1];
  const float* v  = (const float*)d_in[2];
  const float* Wq = (const float*)d_in[3];
  const float* Wk = (const float*)d_in[4];
  const float* Wv = (const float*)d_in[5];
  float* out = (float*)d_out;

  unsigned short* ws  = (unsigned short*)d_ws;
  const size_t ACT = (size_t)4 * 1024 * 1024;
  const size_t WEL = (size_t)1024 * 1024;
  unsigned short* qbf = ws;
  unsigned short* kbf = qbf + ACT;
  unsigned short* vbf = kbf + ACT;
  unsigned short* WqT = vbf + ACT;
  unsigned short* WkT = WqT + WEL;
  unsigned short* WvT = WkT + WEL;
  unsigned short* qwp = WvT + WEL;
  unsigned short* kwp = qwp + ACT;
  unsigned short* vwp = kwp + ACT;
  // attn-phase overlays (dead after gemm_proj):
  unsigned short* vtb   = qbf;            // 8 MB  V^T
  unsigned short* opart = kbf;            // 2560*4096*2B = 20.97 MB (kbf..WkT end)
  float*          mlb   = (float*)WvT;    // 2560*128*4B = 1.31 MB

  cvt_bf16<<<2048, 256, 0, stream>>>(q, qbf, 524288);
  cvt_bf16<<<2048, 256, 0, stream>>>(k, kbf, 524288);
  cvt_bf16<<<2048, 256, 0, stream>>>(v, vbf, 524288);
  trw<<<dim3(32, 32, 3), dim3(32, 32), 0, stream>>>(Wq, Wk, Wv, WqT, WkT, WvT);
  gemm_proj<<<dim3(32, 8, 3), 256, 0, stream>>>(qbf, kbf, vbf, WqT, WkT, WvT,
                                                qwp, kwp, vwp);
  trv<<<dim3(64, 2, 32), dim3(32, 32), 0, stream>>>(vwp, vtb);
  attn<<<dim3(80, 16, 2), 256, 0, stream>>>(qwp, kwp, vtb, opart, mlb, out);
  attn_reduce<<<dim3(24, 16, 2), 256, 0, stream>>>(opart, mlb, out);
}